// Round 8
// baseline (384.760 us; speedup 1.0000x reference)
//
#include <hip/hip_runtime.h>
#include <hip/hip_bf16.h>
#include <cstdint>
#include <cstddef>

// ---- constants (fixed by the reference problem) ----
#define Hh 1024
#define D_EMB 512
#define D_UP 2048
#define BT 16384      // B*T
#define BB_ 512
#define Mm 4096
#define NB 32         // BT/BB
#define KL 64         // K_LABELS
#define NXCD 8
#define PMMAX 8192    // max padded kv rows (labels padded to 64)
#define QROWMAX 17408 // max padded q rows (labels padded to 16)
#define MAXT 1088     // max (label, qtile16) tasks

typedef __attribute__((ext_vector_type(4))) float f4;
typedef __attribute__((ext_vector_type(4))) __bf16 bf4;
typedef __attribute__((ext_vector_type(8))) __bf16 bf8;
typedef __attribute__((ext_vector_type(4))) float f32x4;

// ---------------- helpers ----------------
__device__ __forceinline__ void gl_lds16(const void* g, void* l) {
  __builtin_amdgcn_global_load_lds((__attribute__((address_space(1))) void*)g,
                                   (__attribute__((address_space(3))) void*)l, 16, 0, 0);
}

// ---------------- prep kernels ----------------
__global__ __launch_bounds__(256) void conv_bf16_kernel(const float* __restrict__ src,
                                                        __bf16* __restrict__ dst, int n4) {
  int i = blockIdx.x * 256 + threadIdx.x;
  if (i >= n4) return;
  f4 v = ((const f4*)src)[i];
  bf4 o = {(__bf16)v[0], (__bf16)v[1], (__bf16)v[2], (__bf16)v[3]};
  ((bf4*)dst)[i] = o;
}

__global__ __launch_bounds__(256) void la_kernel(const int* __restrict__ keep,
                                                 const int* __restrict__ emb,
                                                 int* __restrict__ la, int m) {
  int i = blockIdx.x * 256 + threadIdx.x;
  if (i < m) la[i] = emb[keep[i]];
}

__global__ __launch_bounds__(256) void range_kernel(const int* __restrict__ starts,
                                                    const int* __restrict__ ends,
                                                    int* __restrict__ stA, int* __restrict__ enA) {
  int n = blockIdx.x;
  int t = threadIdx.x, lane = t & 63, wv = t >> 6;
  int s1 = min(starts[n * BB_ + t], starts[n * BB_ + t + 256]);
  int e1 = max(ends[n * BB_ + t], ends[n * BB_ + t + 256]);
#pragma unroll
  for (int off = 32; off; off >>= 1) {
    s1 = min(s1, __shfl_xor(s1, off));
    e1 = max(e1, __shfl_xor(e1, off));
  }
  __shared__ int ssh[4], esh[4];
  if (lane == 0) { ssh[wv] = s1; esh[wv] = e1; }
  __syncthreads();
  if (t == 0) {
    int s = ssh[0], e = esh[0];
#pragma unroll
    for (int k = 1; k < 4; ++k) { s = min(s, ssh[k]); e = max(e, esh[k]); }
    stA[n] = s; enA[n] = e;
  }
}

// histogram of labels over all Mm rows + exclusive prefix -> goff[KL+1]
__global__ __launch_bounds__(256) void hist_kernel(const int* __restrict__ la,
                                                   int* __restrict__ goff) {
  __shared__ int cnt[KL];
  int tid = threadIdx.x;
  if (tid < KL) cnt[tid] = 0;
  __syncthreads();
  for (int k = tid; k < Mm; k += 256) atomicAdd(&cnt[la[k]], 1);
  __syncthreads();
  if (tid == 0) {
    int a = 0;
    for (int s = 0; s < KL; ++s) { goff[s] = a; a += cnt[s]; }
    goff[KL] = a;
  }
}

// stable placement: global sorted-by-(label,k) order. one wg per label.
__global__ __launch_bounds__(256) void place_kernel(const int* __restrict__ la,
                                                    const int* __restrict__ keep,
                                                    const int* __restrict__ goff,
                                                    int* __restrict__ gk,
                                                    int* __restrict__ ridx) {
  int s = blockIdx.x;
  int tid = threadIdx.x, lane = tid & 63, wv = tid >> 6;
  __shared__ int wc[4];
  __shared__ int run;
  if (tid == 0) run = goff[s];
  __syncthreads();
  for (int base = 0; base < Mm; base += 256) {
    int k = base + tid;
    bool f = (la[k] == s);
    unsigned long long msk = __ballot(f);
    int myidx = __popcll(msk & ((1ull << lane) - 1ull));
    if (lane == 0) wc[wv] = __popcll(msk);
    __syncthreads();
    int woff = 0, tot = 0;
#pragma unroll
    for (int w = 0; w < 4; ++w) {
      if (w < wv) woff += wc[w];
      tot += wc[w];
    }
    int rbase = run;
    if (f) {
      int p = rbase + woff + myidx;
      gk[p] = k;
      ridx[p] = keep[k];
    }
    __syncthreads();
    if (tid == 0) run = rbase + tot;
    __syncthreads();
  }
}

// counting sort of queries by label within each block of 512
__global__ __launch_bounds__(256) void qsort_kernel(const int* __restrict__ seq_sort,
                                                    int* __restrict__ qidx,
                                                    int* __restrict__ qoffA,
                                                    int* __restrict__ qcntA) {
  int n = blockIdx.x, tid = threadIdx.x;
  __shared__ int cnt[KL], pos[KL], pref[KL];
  if (tid < KL) cnt[tid] = 0;
  __syncthreads();
  int s0 = seq_sort[n * BB_ + tid];
  int s1 = seq_sort[n * BB_ + tid + 256];
  atomicAdd(&cnt[s0], 1);
  atomicAdd(&cnt[s1], 1);
  __syncthreads();
  if (tid == 0) {
    int a = 0;
    for (int s = 0; s < KL; ++s) { pref[s] = a; a += cnt[s]; }
  }
  __syncthreads();
  if (tid < KL) {
    pos[tid] = pref[tid];
    qoffA[n * KL + tid] = pref[tid];
    qcntA[n * KL + tid] = cnt[tid];
  }
  __syncthreads();
  int p0 = atomicAdd(&pos[s0], 1);
  qidx[n * BB_ + p0] = n * BB_ + tid;
  int p1 = atomicAdd(&pos[s1], 1);
  qidx[n * BB_ + p1] = n * BB_ + tid + 256;
}

// metadata: boff/qtot/ptq/pb + natural-order task list
__global__ __launch_bounds__(256) void qmeta_kernel(const int* __restrict__ qcntA,
                                                    const int* __restrict__ goff,
                                                    int* __restrict__ boff,
                                                    int* __restrict__ qtot,
                                                    int* __restrict__ ptq,
                                                    int* __restrict__ pb,
                                                    int* __restrict__ taskS,
                                                    int* __restrict__ taskT,
                                                    int* __restrict__ ntt,
                                                    int* __restrict__ pbTot) {
  int tid = threadIdx.x;
  if (tid < KL) {
    int s = tid, tot = 0;
    for (int n = 0; n < NB; ++n) { boff[n * KL + s] = tot; tot += qcntA[n * KL + s]; }
    qtot[s] = tot;
  }
  __syncthreads();
  if (tid == 0) {
    int tb = 0, tk = 0, pk = 0;
    for (int s = 0; s < KL; ++s) {
      ptq[s] = tb;
      int nt = (qtot[s] + 15) >> 4;
      for (int t2 = 0; t2 < nt; ++t2) { taskS[tk] = s; taskT[tk] = t2; ++tk; }
      tb += nt;
      pb[s] = pk;
      int cnt = goff[s + 1] - goff[s];
      pk += (cnt + 63) & ~63;
    }
    ptq[KL] = tb;
    ntt[0] = tk;
    pbTot[0] = pk;
  }
}

// pridx[p] = source w_k/w_v row for padded pos p (-1 for pad)
__global__ __launch_bounds__(256) void pridx_kernel(const int* __restrict__ goff,
                                                    const int* __restrict__ pb,
                                                    const int* __restrict__ ridx,
                                                    int* __restrict__ pridx) {
  int s = blockIdx.x;
  int cnt = goff[s + 1] - goff[s];
  int padded = (cnt + 63) & ~63;
  int base = pb[s];
  for (int i = threadIdx.x; i < padded; i += 256)
    pridx[base + i] = (i < cnt) ? ridx[goff[s] + i] : -1;
}

// per (block,label): contiguous PADDED sorted-pos range [lo,hi)
__global__ __launch_bounds__(256) void lohi_kernel(const int* __restrict__ gk,
                                                   const int* __restrict__ goff,
                                                   const int* __restrict__ pb,
                                                   const int* __restrict__ stA,
                                                   const int* __restrict__ enA,
                                                   int* __restrict__ loA, int* __restrict__ hiA) {
  int i = blockIdx.x * 256 + threadIdx.x;
  if (i >= NB * KL) return;
  int n = i / KL, s = i % KL;
  int b = goff[s], e = goff[s + 1];
  int st = stA[n], en = enA[n];
  int lo = b, hi = e;
  while (lo < hi) { int mid = (lo + hi) >> 1; if (gk[mid] < st) lo = mid + 1; else hi = mid; }
  int L = lo;
  lo = b; hi = e;
  while (lo < hi) { int mid = (lo + hi) >> 1; if (gk[mid] < en) lo = mid + 1; else hi = mid; }
  loA[i] = pb[s] + (L - goff[s]);
  hiA[i] = pb[s] + (lo - goff[s]);
}

// global label-sorted q order + inverse map
__global__ __launch_bounds__(256) void gq_kernel(const int* __restrict__ qidx,
                                                 const int* __restrict__ qoffA,
                                                 const int* __restrict__ seq_sort,
                                                 const int* __restrict__ boff,
                                                 const int* __restrict__ ptq,
                                                 int* __restrict__ qg2, int* __restrict__ gq) {
  int e = blockIdx.x * 256 + threadIdx.x;
  int n = e >> 9;
  int q = qidx[e];
  int s = seq_sort[q];
  int i = (e & 511) - qoffA[n * KL + s];
  int gpos = ptq[s] * 16 + boff[n * KL + s] + i;
  qg2[gpos] = q;
  gq[q] = gpos;
}

// zero the label-tail pad rows of Qsw (deterministic each launch)
__global__ __launch_bounds__(256) void qzero_kernel(const int* __restrict__ ptq,
                                                    const int* __restrict__ qtot,
                                                    __bf16* __restrict__ Qsw) {
  int s = blockIdx.x;
  int b0 = ptq[s] * 16 + qtot[s];
  int b1 = ptq[s + 1] * 16;
  bf8 z;
#pragma unroll
  for (int j = 0; j < 8; ++j) z[j] = (__bf16)0.f;
  for (int r = b0; r < b1; ++r)
    for (int e8 = threadIdx.x; e8 < 128; e8 += 256)
      *(bf8*)&Qsw[(size_t)r * 1024 + e8 * 8] = z;
}

// Ksw[pt][ks][lane][8] = K[pt*16 + (lane&15)][ks*32 + (lane>>4)*8 + i] (bf16; pad rows zero)
__global__ __launch_bounds__(256) void kswb_kernel(const float* __restrict__ wk,
                                                   const int* __restrict__ pridx,
                                                   const int* __restrict__ pbTot,
                                                   __bf16* __restrict__ Ksw) {
  int pt = blockIdx.x;
  if (pt * 16 >= pbTot[0]) return;
  __shared__ __bf16 Tk[16][1040];
  int tid = threadIdx.x;
  int rr = tid >> 4, lt = tid & 15;
  int src = pridx[pt * 16 + rr];
  for (int cc = 0; cc < 16; ++cc) {
    int i4 = cc * 16 + lt;
    f4 v = {0.f, 0.f, 0.f, 0.f};
    if (src >= 0) v = ((const f4*)(wk + (size_t)src * Hh))[i4];
    bf4 o = {(__bf16)v[0], (__bf16)v[1], (__bf16)v[2], (__bf16)v[3]};
    *(bf4*)&Tk[rr][i4 * 4] = o;
  }
  __syncthreads();
#pragma unroll
  for (int i = 0; i < 8; ++i) {
    int f = tid + 256 * i;
    int ks = f >> 6, ln = f & 63;
    int c2 = ln & 15, rg2 = ln >> 4;
    bf8 o = *(const bf8*)&Tk[c2][ks * 32 + rg2 * 8];
    *(bf8*)&Ksw[(size_t)pt * 16384 + (size_t)f * 8] = o;
  }
}

// Vsw[pblk][ff][lane][8] = V^T[ff*16 + (lane&15)][pblk*32 + (lane>>4)*8 + i]
__global__ __launch_bounds__(256) void vswb_kernel(const float* __restrict__ wv_,
                                                   const int* __restrict__ pridx,
                                                   const int* __restrict__ pbTot,
                                                   __bf16* __restrict__ Vsw) {
  int pblk = blockIdx.x;
  if (pblk * 32 >= pbTot[0]) return;
  __shared__ __bf16 Tv[32][528];
  int tid = threadIdx.x;
  int rr = tid >> 3, lt = tid & 7;
  int src = pridx[pblk * 32 + rr];
  for (int cc = 0; cc < 16; ++cc) {
    int i4 = cc * 8 + lt;
    f4 v = {0.f, 0.f, 0.f, 0.f};
    if (src >= 0) v = ((const f4*)(wv_ + (size_t)src * D_EMB))[i4];
    bf4 o = {(__bf16)v[0], (__bf16)v[1], (__bf16)v[2], (__bf16)v[3]};
    *(bf4*)&Tv[rr][i4 * 4] = o;
  }
  __syncthreads();
#pragma unroll
  for (int i = 0; i < 8; ++i) {
    int f = tid + 256 * i;
    int ff = f >> 6, ln = f & 63;
    int c2 = ln & 15, rg2 = ln >> 4;
    bf8 o;
#pragma unroll
    for (int j = 0; j < 8; ++j) o[j] = Tv[rg2 * 8 + j][ff * 16 + c2];
    *(bf8*)&Vsw[(size_t)pblk * 16384 + (size_t)f * 8] = o;
  }
}

// ---------------- RMSNorm of input: inb[j] = bf16(input[j]); Qsw row gq[bw[j]] ----------------
__global__ __launch_bounds__(256) void rms_in_kernel(const float* __restrict__ input,
                                                     const int* __restrict__ bw,
                                                     const int* __restrict__ gq,
                                                     const float* __restrict__ wn,
                                                     __bf16* __restrict__ Qsw,
                                                     __bf16* __restrict__ inb) {
  __shared__ __align__(16) __bf16 rowbuf[4][1024];
  int wv = threadIdx.x >> 6, lane = threadIdx.x & 63;
  int j = blockIdx.x * 4 + wv;
  const f4* src = (const f4*)(input + (size_t)j * Hh);
  f4 v[4];
  float ss = 0.f;
#pragma unroll
  for (int c = 0; c < 4; ++c) {
    v[c] = src[c * 64 + lane];
    ss += v[c][0] * v[c][0] + v[c][1] * v[c][1] + v[c][2] * v[c][2] + v[c][3] * v[c][3];
  }
#pragma unroll
  for (int off = 32; off; off >>= 1) ss += __shfl_xor(ss, off);
  float sc = rsqrtf(ss * (1.f / Hh) + 1e-6f);
  bf4* dstI = (bf4*)(inb + (size_t)j * Hh);
#pragma unroll
  for (int c = 0; c < 4; ++c) {
    bf4 o = {(__bf16)v[c][0], (__bf16)v[c][1], (__bf16)v[c][2], (__bf16)v[c][3]};
    dstI[c * 64 + lane] = o;
  }
  const f4* w4 = (const f4*)wn;
#pragma unroll
  for (int c = 0; c < 4; ++c) {
    f4 w = w4[c * 64 + lane];
    bf4 o = {(__bf16)(v[c][0] * sc * w[0]), (__bf16)(v[c][1] * sc * w[1]),
             (__bf16)(v[c][2] * sc * w[2]), (__bf16)(v[c][3] * sc * w[3])};
    *(bf4*)&rowbuf[wv][(c * 64 + lane) * 4] = o;
  }
  int gpos = gq[bw[j]];
  int qt2 = gpos >> 4, cq = gpos & 15;
#pragma unroll
  for (int h = 0; h < 2; ++h) {
    int k_ = lane + h * 64;
    int ks = k_ >> 2, rg2 = k_ & 3;
    bf8 o = *(const bf8*)&rowbuf[wv][ks * 32 + rg2 * 8];
    *(bf8*)(Qsw + (size_t)qt2 * 16384 + ks * 512 + (cq + 16 * rg2) * 8) = o;
  }
}

// ---------------- cooperative 4-wave attention: workgroup per (label, qtile16) ----------------
// QK^T: wave wv computes kv-subtile wv (32 MFMA, coalesced frags) -> S in LDS.
// Softmax: wave wv owns q rows wv*4..+3 (m/l in registers), P -> LDS bf16.
// PV: wave wv owns d slice [wv*128, wv*128+128): acc[8], coalesced Vsw frags.
__global__ __launch_bounds__(256, 3) void attn7_kernel(const __bf16* __restrict__ Qsw,
                                                       const __bf16* __restrict__ Ksw,
                                                       const __bf16* __restrict__ Vsw,
                                                       const int* __restrict__ qg2,
                                                       const int* __restrict__ qtot,
                                                       const int* __restrict__ ptq,
                                                       const int* __restrict__ taskS,
                                                       const int* __restrict__ taskT,
                                                       const int* __restrict__ nttA,
                                                       const int* __restrict__ pb,
                                                       const int* __restrict__ loP,
                                                       const int* __restrict__ hiP,
                                                       const int* __restrict__ fw,
                                                       __bf16* __restrict__ comb) {
  __shared__ float Sb[16][66];
  __shared__ __align__(16) __bf16 Plds[16][72];
  __shared__ float scl_s[16], lrec[16];
  __shared__ __align__(16) __bf16 owb[16][528];
  int t = blockIdx.x;
  if (t >= nttA[0]) return;
  int tid = threadIdx.x, wv = tid >> 6, lane = tid & 63;
  int c = lane & 15, rg = lane >> 4;
  int s = taskS[t], tl = taskT[t];
  int qtp = ptq[s] + tl;
  int qcnt = min(16, qtot[s] - tl * 16);
  bool qv = c < qcnt;
  int q_l = qg2[qtp * 16 + (qv ? c : 0)];
  int n_l = q_l >> 9;
  int lo_l = qv ? loP[n_l * KL + s] : 0x7fffffff;
  int hi_l = qv ? hiP[n_l * KL + s] : 0;
  int tlo = lo_l, thi = hi_l;
#pragma unroll
  for (int off = 1; off < 64; off <<= 1) {
    tlo = min(tlo, __shfl_xor(tlo, off));
    thi = max(thi, __shfl_xor(thi, off));
  }
  if (tlo >= thi) return;
  int pbs = pb[s];
  const __bf16* Qb = Qsw + (size_t)qtp * 16384 + lane * 8;

  float m[4] = {-1e30f, -1e30f, -1e30f, -1e30f};
  float l[4] = {0.f, 0.f, 0.f, 0.f};
  f32x4 acc[8];
  f32x4 zero = {0.f, 0.f, 0.f, 0.f};
#pragma unroll
  for (int tt = 0; tt < 8; ++tt) acc[tt] = zero;

  int p0beg = pbs + ((tlo - pbs) & ~63);
  for (int p0 = p0beg; p0 < thi; p0 += 64) {
    // ---- QK^T: this wave's kv-subtile -> C[kv][q] (col = q = c) ----
    const __bf16* Kb = Ksw + (size_t)((p0 >> 4) + wv) * 16384 + lane * 8;
    f32x4 sacc = zero;
#pragma unroll
    for (int ks = 0; ks < 32; ++ks) {
      bf8 qf = *(const bf8*)(Qb + ks * 512);
      bf8 kf = *(const bf8*)(Kb + ks * 512);
      sacc = __builtin_amdgcn_mfma_f32_16x16x32_bf16(kf, qf, sacc, 0, 0, 0);
    }
#pragma unroll
    for (int r = 0; r < 4; ++r) {
      int kv = p0 + wv * 16 + rg * 4 + r;
      Sb[c][wv * 16 + rg * 4 + r] = (kv >= lo_l && kv < hi_l) ? sacc[r] : -1e30f;
    }
    __syncthreads();

    // ---- online softmax: wave wv owns q rows wv*4..+3, lane = kv 0..63 ----
#pragma unroll
    for (int r = 0; r < 4; ++r) {
      int q = wv * 4 + r;
      float sv = Sb[q][lane];
      float cm = sv;
#pragma unroll
      for (int off = 32; off; off >>= 1) cm = fmaxf(cm, __shfl_xor(cm, off));
      float mn = fmaxf(m[r], cm);
      float sc2 = __expf(m[r] - mn);
      float pv = __expf(sv - mn);
      float ssum = pv;
#pragma unroll
      for (int off = 32; off; off >>= 1) ssum += __shfl_xor(ssum, off);
      l[r] = l[r] * sc2 + ssum;
      m[r] = mn;
      Plds[q][lane] = (__bf16)pv;
      if (lane == 0) scl_s[q] = sc2;
    }
    __syncthreads();

    // ---- rescale + PV: wave wv owns d in [wv*128, wv*128+128) ----
    float sf = scl_s[c];
#pragma unroll
    for (int tt = 0; tt < 8; ++tt) acc[tt] = acc[tt] * sf;
    bf8 pa0 = *(const bf8*)&Plds[c][rg * 8];
    bf8 pa1 = *(const bf8*)&Plds[c][32 + rg * 8];
    const __bf16* Vb = Vsw + (size_t)(p0 >> 5) * 16384 + lane * 8;
#pragma unroll
    for (int tt = 0; tt < 8; ++tt) {
      int ff = wv * 8 + tt;
      bf8 v0 = *(const bf8*)(Vb + ff * 512);
      bf8 v1 = *(const bf8*)(Vb + 16384 + ff * 512);
      acc[tt] = __builtin_amdgcn_mfma_f32_16x16x32_bf16(v0, pa0, acc[tt], 0, 0, 0);
      acc[tt] = __builtin_amdgcn_mfma_f32_16x16x32_bf16(v1, pa1, acc[tt], 0, 0, 0);
    }
    __syncthreads();  // protect Sb/Plds/scl_s for next chunk
  }

  // ---- epilogue ----
  if (lane == 0) {
#pragma unroll
    for (int r = 0; r < 4; ++r) lrec[wv * 4 + r] = l[r];
  }
  __syncthreads();
  float inv = 1.f / lrec[c];
#pragma unroll
  for (int tt = 0; tt < 8; ++tt) {
    bf4 o;
#pragma unroll
    for (int r = 0; r < 4; ++r) o[r] = (__bf16)(acc[tt][r] * inv);
    *(bf4*)&owb[c][(wv * 8 + tt) * 16 + rg * 4] = o;
  }
  __syncthreads();
#pragma unroll
  for (int r4 = 0; r4 < 4; ++r4) {
    int q2 = wv * 4 + r4;
    if (q2 < qcnt) {
      size_t ob = (size_t)fw[qg2[qtp * 16 + q2]] * D_EMB;
      *(bf8*)(comb + ob + lane * 8) = *(const bf8*)&owb[q2][lane * 8];
    }
  }
}

// ---------------- 256x256 ring-pipelined GEMM, ONE barrier per 32-MFMA tile ----------------
template <bool OUT_BF16>
__global__ __launch_bounds__(512, 2) void gemm9(const __bf16* __restrict__ x0, int k0,
                                                const __bf16* __restrict__ x1, int k1,
                                                const __bf16* __restrict__ w,
                                                void* __restrict__ outp, int Mt, int Nt) {
  __shared__ __align__(16) __bf16 lds[4][2][256 * 32];
  const int nwg = Mt * Nt;
  const int bid = blockIdx.x;
  const int swz = (bid % NXCD) * (nwg / NXCD) + bid / NXCD;
  const int m0 = (swz / Nt) * 256, n0 = (swz % Nt) * 256;
  const int K = k0 + k1;
  const int NT = K >> 5;
  const int N = Nt * 256;
  const int tid = threadIdx.x, lane = tid & 63, wvi = tid >> 6;
  const int wr = wvi >> 2, wc = wvi & 3;
  const int srow = tid >> 2;
  const int spb = (tid & 3) * 16;
  const int c = lane & 15, rg = lane >> 4;
  const int fa_off = c * 64 + ((rg ^ ((c >> 1) & 3)) << 4);

  auto stage = [&](int t) {
    int kg = t * 32;
    const __bf16* xs;
    int ld, kk;
    if (kg < k0) { xs = x0; ld = k0; kk = kg; }
    else         { xs = x1; ld = k1; kk = kg - k0; }
    int b = t & 3;
#pragma unroll
    for (int j = 0; j < 2; ++j) {
      int r = j * 128 + srow;
      int lcol = (spb ^ (((r >> 1) & 3) << 4)) >> 1;
      gl_lds16(xs + (size_t)(m0 + r) * ld + kk + lcol,
               (void*)((char*)&lds[b][0][0] + r * 64 + spb));
      gl_lds16(w + (size_t)(n0 + r) * K + kg + lcol,
               (void*)((char*)&lds[b][1][0] + r * 64 + spb));
    }
  };

  f32x4 acc[8][4];
  f32x4 zero = {0.f, 0.f, 0.f, 0.f};
#pragma unroll
  for (int a = 0; a < 8; ++a)
#pragma unroll
    for (int bnx = 0; bnx < 4; ++bnx) acc[a][bnx] = zero;

  auto compute = [&](int t) {
    const char* Ab = (const char*)&lds[t & 3][0][0];
    const char* Bb = (const char*)&lds[t & 3][1][0];
    bf8 afr[8], bfr[4];
#pragma unroll
    for (int fi = 0; fi < 8; ++fi)
      afr[fi] = *(const bf8*)(Ab + (wr * 128 + fi * 16) * 64 + fa_off);
#pragma unroll
    for (int ni = 0; ni < 4; ++ni)
      bfr[ni] = *(const bf8*)(Bb + (wc * 64 + ni * 16) * 64 + fa_off);
    __builtin_amdgcn_s_setprio(1);
#pragma unroll
    for (int fi = 0; fi < 8; ++fi)
#pragma unroll
      for (int ni = 0; ni < 4; ++ni)
        acc[fi][ni] = __builtin_amdgcn_mfma_f32_16x16x32_bf16(afr[fi], bfr[ni], acc[fi][ni], 0, 0, 0);
    __builtin_amdgcn_s_setprio(0);
  };

  stage(0); stage(1); stage(2);
  asm volatile("s_waitcnt vmcnt(8)" ::: "memory");
  __builtin_amdgcn_s_barrier();

  for (int t = 0; t < NT - 3; ++t) {
    stage(t + 3);
    compute(t);
    asm volatile("s_waitcnt vmcnt(8)" ::: "memory");
    __builtin_amdgcn_s_barrier();
  }
  compute(NT - 3);
  asm volatile("s_waitcnt vmcnt(4)" ::: "memory");
  __builtin_amdgcn_s_barrier();
  compute(NT - 2);
  asm volatile("s_waitcnt vmcnt(0)" ::: "memory");
  __builtin_amdgcn_s_barrier();
  compute(NT - 1);

  const int r0 = (lane >> 4) * 4, cc = lane & 15;
#pragma unroll
  for (int mi = 0; mi < 8; ++mi) {
    int rowb = m0 + wr * 128 + mi * 16 + r0;
#pragma unroll
    for (int ni = 0; ni < 4; ++ni) {
      int col = n0 + wc * 64 + ni * 16 + cc;
#pragma unroll
      for (int r = 0; r < 4; ++r) {
        float v = acc[mi][ni][r];
        if (OUT_BF16)
          ((__bf16*)outp)[(size_t)(rowb + r) * N + col] = (__bf16)v;
        else
          ((float*)outp)[(size_t)(rowb + r) * N + col] = v;
      }
    }
  }
}

// ---------------- in-place RMSNorm of up ----------------
__global__ __launch_bounds__(256) void rms_up_kernel(__bf16* __restrict__ up,
                                                     const float* __restrict__ wn) {
  int wv = threadIdx.x >> 6, lane = threadIdx.x & 63;
  size_t j = (size_t)blockIdx.x * 4 + wv;
  bf8* row = (bf8*)(up + j * D_UP);
  bf8 v[4];
  float ss = 0.f;
#pragma unroll
  for (int c = 0; c < 4; ++c) {
    v[c] = row[c * 64 + lane];
#pragma unroll
    for (int i = 0; i < 8; ++i) { float f = (float)v[c][i]; ss += f * f; }
  }
#pragma unroll
  for (int off = 32; off; off >>= 1) ss += __shfl_xor(ss, off);
  float sc = rsqrtf(ss * (1.f / D_UP) + 1e-6f);
#pragma unroll
  for (int c = 0; c < 4; ++c) {
    int ebase = (c * 64 + lane) * 8;
    f4 wa = *(const f4*)(wn + ebase);
    f4 wb = *(const f4*)(wn + ebase + 4);
    bf8 o;
#pragma unroll
    for (int i = 0; i < 4; ++i) o[i] = (__bf16)((float)v[c][i] * sc * wa[i]);
#pragma unroll
    for (int i = 0; i < 4; ++i) o[4 + i] = (__bf16)((float)v[c][4 + i] * sc * wb[i]);
    row[c * 64 + lane] = o;
  }
}

// ---------------- launch ----------------
extern "C" void kernel_launch(void* const* d_in, const int* in_sizes, int n_in, void* d_out,
                              int out_size, void* d_ws, size_t ws_size, hipStream_t stream) {
  const float* input = (const float*)d_in[0];
  const int* fw = (const int*)d_in[1];
  const int* bw = (const int*)d_in[2];
  const int* seq_sort = (const int*)d_in[3];
  const int* keep_cols = (const int*)d_in[4];
  const int* emb_alloc = (const int*)d_in[5];
  const int* starts = (const int*)d_in[6];
  const int* ends = (const int*)d_in[7];
  const float* w_k = (const float*)d_in[9];
  const float* w_v = (const float*)d_in[10];
  const float* w_up = (const float*)d_in[11];
  const float* w_mix = (const float*)d_in[12];
  const float* w_nin = (const float*)d_in[13];
  const float* w_nout = (const float*)d_in[14];

  char* p = (char*)d_ws;
  auto take = [&](size_t b) {
    void* r = (void*)p;
    p += (b + 255) & ~(size_t)255;
    return r;
  };
  // region A: persistent through the whole pipeline
  __bf16* inb = (__bf16*)take((size_t)BT * Hh * 2);
  __bf16* comb = (__bf16*)take((size_t)BT * D_EMB * 2);
  __bf16* wupB = (__bf16*)take((size_t)D_UP * D_EMB * 2);
  __bf16* wmixB = (__bf16*)take((size_t)Hh * (D_UP + Hh) * 2);
  // region B: attention-phase only; `up` aliases it afterwards
  char* pB = p;
  __bf16* Ksw = (__bf16*)take((size_t)PMMAX * 1024 * 2);
  __bf16* Vsw = (__bf16*)take((size_t)PMMAX * 512 * 2);
  __bf16* Qsw = (__bf16*)take((size_t)QROWMAX * 1024 * 2);
  int* la = (int*)take(Mm * 4);
  int* stA = (int*)take(NB * 4);
  int* enA = (int*)take(NB * 4);
  int* goff = (int*)take((KL + 1) * 4);
  int* gk = (int*)take(Mm * 4);
  int* ridx = (int*)take(Mm * 4);
  int* pridx = (int*)take(PMMAX * 4);
  int* loA = (int*)take(NB * KL * 4);
  int* hiA = (int*)take(NB * KL * 4);
  int* qidx = (int*)take(BT * 4);
  int* qoffA = (int*)take(NB * KL * 4);
  int* qcntA = (int*)take(NB * KL * 4);
  int* boff = (int*)take(NB * KL * 4);
  int* qtot = (int*)take(KL * 4);
  int* ptq = (int*)take((KL + 1) * 4);
  int* pb = (int*)take(KL * 4);
  int* taskS = (int*)take(MAXT * 4);
  int* taskT = (int*)take(MAXT * 4);
  int* ntt = (int*)take(4);
  int* pbTot = (int*)take(4);
  int* qg2 = (int*)take(QROWMAX * 4);
  int* gq = (int*)take(BT * 4);
  // up aliases region B (dead after attn7); regenerated every launch
  __bf16* up = (__bf16*)pB;

  // prep
  conv_bf16_kernel<<<(D_UP * D_EMB / 4 + 255) / 256, 256, 0, stream>>>(w_up, wupB, D_UP * D_EMB / 4);
  conv_bf16_kernel<<<(Hh * (D_UP + Hh) / 4 + 255) / 256, 256, 0, stream>>>(w_mix, wmixB,
                                                                           Hh * (D_UP + Hh) / 4);
  la_kernel<<<Mm / 256, 256, 0, stream>>>(keep_cols, emb_alloc, la, Mm);
  range_kernel<<<NB, 256, 0, stream>>>(starts, ends, stA, enA);
  hist_kernel<<<1, 256, 0, stream>>>(la, goff);
  qsort_kernel<<<NB, 256, 0, stream>>>(seq_sort, qidx, qoffA, qcntA);
  place_kernel<<<KL, 256, 0, stream>>>(la, keep_cols, goff, gk, ridx);
  qmeta_kernel<<<1, 256, 0, stream>>>(qcntA, goff, boff, qtot, ptq, pb, taskS, taskT, ntt, pbTot);
  pridx_kernel<<<KL, 256, 0, stream>>>(goff, pb, ridx, pridx);
  lohi_kernel<<<(NB * KL + 255) / 256, 256, 0, stream>>>(gk, goff, pb, stA, enA, loA, hiA);
  gq_kernel<<<BT / 256, 256, 0, stream>>>(qidx, qoffA, seq_sort, boff, ptq, qg2, gq);
  qzero_kernel<<<KL, 256, 0, stream>>>(ptq, qtot, Qsw);
  kswb_kernel<<<PMMAX / 16, 256, 0, stream>>>(w_k, pridx, pbTot, Ksw);
  vswb_kernel<<<PMMAX / 32, 256, 0, stream>>>(w_v, pridx, pbTot, Vsw);

  // pipeline
  rms_in_kernel<<<BT / 4, 256, 0, stream>>>(input, bw, gq, w_nin, Qsw, inb);
  attn7_kernel<<<MAXT, 256, 0, stream>>>(Qsw, Ksw, Vsw, qg2, qtot, ptq, taskS, taskT, ntt, pb,
                                         loA, hiA, fw, comb);
  gemm9<true><<<BT / 256 * (D_UP / 256), 512, 0, stream>>>(comb, D_EMB, (const __bf16*)nullptr, 0,
                                                           wupB, (void*)up, BT / 256, D_UP / 256);
  rms_up_kernel<<<BT / 4, 256, 0, stream>>>(up, w_nout);
  gemm9<false><<<BT / 256 * (Hh / 256), 512, 0, stream>>>(up, D_UP, inb, Hh, wmixB, d_out,
                                                          BT / 256, Hh / 256);
}

// Round 9
// 342.380 us; speedup vs baseline: 1.1238x; 1.1238x over previous
//
#include <hip/hip_runtime.h>
#include <hip/hip_bf16.h>
#include <cstdint>
#include <cstddef>

// ---- constants (fixed by the reference problem) ----
#define Hh 1024
#define D_EMB 512
#define D_UP 2048
#define BT 16384      // B*T
#define BB_ 512
#define Mm 4096
#define NB 32         // BT/BB
#define KL 64         // K_LABELS
#define NXCD 8
#define PMMAX 8192    // max padded kv rows (labels padded to 64)
#define QROWMAX 17408 // max padded q rows (labels padded to 16)
#define MAXT 1088     // max (label, qtile16) tasks

typedef __attribute__((ext_vector_type(4))) float f4;
typedef __attribute__((ext_vector_type(4))) __bf16 bf4;
typedef __attribute__((ext_vector_type(8))) __bf16 bf8;
typedef __attribute__((ext_vector_type(4))) float f32x4;

// ---------------- helpers ----------------
__device__ __forceinline__ void gl_lds16(const void* g, void* l) {
  __builtin_amdgcn_global_load_lds((__attribute__((address_space(1))) void*)g,
                                   (__attribute__((address_space(3))) void*)l, 16, 0, 0);
}

// ================= K1: conv_up + conv_mix(*w_nout) + la + range + qsort + ssq-zero ==========
__global__ __launch_bounds__(256) void k1_misc(const float* __restrict__ w_up,
                                               const float* __restrict__ w_mix,
                                               const float* __restrict__ w_nout,
                                               const int* __restrict__ keep,
                                               const int* __restrict__ emb,
                                               const int* __restrict__ starts,
                                               const int* __restrict__ ends,
                                               const int* __restrict__ seq_sort,
                                               __bf16* __restrict__ wupB,
                                               __bf16* __restrict__ wmixB,
                                               int* __restrict__ la,
                                               int* __restrict__ stA, int* __restrict__ enA,
                                               int* __restrict__ qidx,
                                               int* __restrict__ qoffA, int* __restrict__ qcntA,
                                               float* __restrict__ rowssq) {
  __shared__ int ssh[4], esh[4];
  __shared__ int cnt[KL], pos[KL], pref[KL];
  int b = blockIdx.x, tid = threadIdx.x;
  if (b < 1024) {                    // conv w_up -> bf16
    int i = b * 256 + tid;
    f4 v = ((const f4*)w_up)[i];
    bf4 o = {(__bf16)v[0], (__bf16)v[1], (__bf16)v[2], (__bf16)v[3]};
    ((bf4*)wupB)[i] = o;
  } else if (b < 4096) {             // conv w_mix -> bf16, fold w_nout into k<2048 cols
    int i = (b - 1024) * 256 + tid;
    f4 v = ((const f4*)w_mix)[i];
    int kq = i % 768;                // 3072/4
    if (kq < 512) {
      f4 wn = ((const f4*)w_nout)[kq];
      v[0] *= wn[0]; v[1] *= wn[1]; v[2] *= wn[2]; v[3] *= wn[3];
    }
    bf4 o = {(__bf16)v[0], (__bf16)v[1], (__bf16)v[2], (__bf16)v[3]};
    ((bf4*)wmixB)[i] = o;
  } else if (b < 4112) {             // la
    int i = (b - 4096) * 256 + tid;
    if (i < Mm) la[i] = emb[keep[i]];
  } else if (b < 4144) {             // range
    int n = b - 4112;
    int lane = tid & 63, wv = tid >> 6;
    int s1 = min(starts[n * BB_ + tid], starts[n * BB_ + tid + 256]);
    int e1 = max(ends[n * BB_ + tid], ends[n * BB_ + tid + 256]);
#pragma unroll
    for (int off = 32; off; off >>= 1) {
      s1 = min(s1, __shfl_xor(s1, off));
      e1 = max(e1, __shfl_xor(e1, off));
    }
    if (lane == 0) { ssh[wv] = s1; esh[wv] = e1; }
    __syncthreads();
    if (tid == 0) {
      int s = ssh[0], e = esh[0];
#pragma unroll
      for (int k = 1; k < 4; ++k) { s = min(s, ssh[k]); e = max(e, esh[k]); }
      stA[n] = s; enA[n] = e;
    }
  } else if (b < 4176) {             // qsort per block n
    int n = b - 4144;
    if (tid < KL) cnt[tid] = 0;
    __syncthreads();
    int s0 = seq_sort[n * BB_ + tid];
    int s1 = seq_sort[n * BB_ + tid + 256];
    atomicAdd(&cnt[s0], 1);
    atomicAdd(&cnt[s1], 1);
    __syncthreads();
    if (tid == 0) {
      int a = 0;
      for (int s = 0; s < KL; ++s) { pref[s] = a; a += cnt[s]; }
    }
    __syncthreads();
    if (tid < KL) {
      pos[tid] = pref[tid];
      qoffA[n * KL + tid] = pref[tid];
      qcntA[n * KL + tid] = cnt[tid];
    }
    __syncthreads();
    int p0 = atomicAdd(&pos[s0], 1);
    qidx[n * BB_ + p0] = n * BB_ + tid;
    int p1 = atomicAdd(&pos[s1], 1);
    qidx[n * BB_ + p1] = n * BB_ + tid + 256;
  } else {                            // zero rowssq (16384 f32)
    int i = (b - 4176) * 256 + tid;
    if (i < 4096) { f4 z = {0.f, 0.f, 0.f, 0.f}; ((f4*)rowssq)[i] = z; }
  }
}

// ================= K2: hist + goff prefix + boff/qtot + ptq/pb/tasks (single block) =========
__global__ __launch_bounds__(256) void k2_meta(const int* __restrict__ la,
                                               const int* __restrict__ qcntA,
                                               int* __restrict__ goff,
                                               int* __restrict__ boff, int* __restrict__ qtot,
                                               int* __restrict__ ptq, int* __restrict__ pb,
                                               int* __restrict__ taskS, int* __restrict__ taskT,
                                               int* __restrict__ ntt, int* __restrict__ pbTot) {
  __shared__ int cnt[KL];
  int tid = threadIdx.x;
  if (tid < KL) cnt[tid] = 0;
  __syncthreads();
  for (int k = tid; k < Mm; k += 256) atomicAdd(&cnt[la[k]], 1);
  if (tid < KL) {
    int s = tid, tot = 0;
    for (int n = 0; n < NB; ++n) { boff[n * KL + s] = tot; tot += qcntA[n * KL + s]; }
    qtot[s] = tot;
  }
  __syncthreads();
  if (tid == 0) {
    int a = 0;
    for (int s = 0; s < KL; ++s) { goff[s] = a; a += cnt[s]; }
    goff[KL] = a;
    int tb = 0, tk = 0, pk = 0;
    for (int s = 0; s < KL; ++s) {
      ptq[s] = tb;
      int nt = (qtot[s] + 15) >> 4;
      for (int t2 = 0; t2 < nt; ++t2) { taskS[tk] = s; taskT[tk] = t2; ++tk; }
      tb += nt;
      pb[s] = pk;
      int c2 = goff[s + 1] - goff[s];
      pk += (c2 + 63) & ~63;
    }
    ptq[KL] = tb;
    ntt[0] = tk;
    pbTot[0] = pk;
  }
}

// ================= K3: stable placement (unchanged) =========================================
__global__ __launch_bounds__(256) void place_kernel(const int* __restrict__ la,
                                                    const int* __restrict__ keep,
                                                    const int* __restrict__ goff,
                                                    int* __restrict__ gk,
                                                    int* __restrict__ ridx) {
  int s = blockIdx.x;
  int tid = threadIdx.x, lane = tid & 63, wv = tid >> 6;
  __shared__ int wc[4];
  __shared__ int run;
  if (tid == 0) run = goff[s];
  __syncthreads();
  for (int base = 0; base < Mm; base += 256) {
    int k = base + tid;
    bool f = (la[k] == s);
    unsigned long long msk = __ballot(f);
    int myidx = __popcll(msk & ((1ull << lane) - 1ull));
    if (lane == 0) wc[wv] = __popcll(msk);
    __syncthreads();
    int woff = 0, tot = 0;
#pragma unroll
    for (int w = 0; w < 4; ++w) {
      if (w < wv) woff += wc[w];
      tot += wc[w];
    }
    int rbase = run;
    if (f) {
      int p = rbase + woff + myidx;
      gk[p] = k;
      ridx[p] = keep[k];
    }
    __syncthreads();
    if (tid == 0) run = rbase + tot;
    __syncthreads();
  }
}

// ================= K4: pridx + lohi + gq + qzero ============================================
__global__ __launch_bounds__(256) void k4_idx(const int* __restrict__ goff,
                                              const int* __restrict__ pb,
                                              const int* __restrict__ ridx,
                                              int* __restrict__ pridx,
                                              const int* __restrict__ gk,
                                              const int* __restrict__ stA,
                                              const int* __restrict__ enA,
                                              int* __restrict__ loA, int* __restrict__ hiA,
                                              const int* __restrict__ qidx,
                                              const int* __restrict__ qoffA,
                                              const int* __restrict__ seq_sort,
                                              const int* __restrict__ boff,
                                              const int* __restrict__ ptq,
                                              int* __restrict__ qg2, int* __restrict__ gq,
                                              const int* __restrict__ qtot,
                                              __bf16* __restrict__ Qsw) {
  int b = blockIdx.x, tid = threadIdx.x;
  if (b < 64) {                       // pridx
    int s = b;
    int cnt2 = goff[s + 1] - goff[s];
    int padded = (cnt2 + 63) & ~63;
    int base = pb[s];
    for (int i = tid; i < padded; i += 256)
      pridx[base + i] = (i < cnt2) ? ridx[goff[s] + i] : -1;
  } else if (b < 72) {                // lohi
    int i = (b - 64) * 256 + tid;
    if (i < NB * KL) {
      int n = i / KL, s = i % KL;
      int b0 = goff[s], e0 = goff[s + 1];
      int st = stA[n], en = enA[n];
      int lo = b0, hi = e0;
      while (lo < hi) { int mid = (lo + hi) >> 1; if (gk[mid] < st) lo = mid + 1; else hi = mid; }
      int L = lo;
      lo = b0; hi = e0;
      while (lo < hi) { int mid = (lo + hi) >> 1; if (gk[mid] < en) lo = mid + 1; else hi = mid; }
      loA[i] = pb[s] + (L - goff[s]);
      hiA[i] = pb[s] + (lo - goff[s]);
    }
  } else if (b < 136) {               // gq
    int e = (b - 72) * 256 + tid;
    int n = e >> 9;
    int q = qidx[e];
    int s = seq_sort[q];
    int i = (e & 511) - qoffA[n * KL + s];
    int gpos = ptq[s] * 16 + boff[n * KL + s] + i;
    qg2[gpos] = q;
    gq[q] = gpos;
  } else {                            // qzero
    int s = b - 136;
    int b0 = ptq[s] * 16 + qtot[s];
    int b1 = ptq[s + 1] * 16;
    bf8 z;
#pragma unroll
    for (int j = 0; j < 8; ++j) z[j] = (__bf16)0.f;
    for (int r = b0; r < b1; ++r)
      for (int e8 = tid; e8 < 128; e8 += 256)
        *(bf8*)&Qsw[(size_t)r * 1024 + e8 * 8] = z;
  }
}

// ================= K5: Ksw build + Vsw build ================================================
__global__ __launch_bounds__(256) void k5_build(const float* __restrict__ wk,
                                                const float* __restrict__ wv_,
                                                const int* __restrict__ pridx,
                                                const int* __restrict__ pbTot,
                                                __bf16* __restrict__ Ksw,
                                                __bf16* __restrict__ Vsw) {
  __shared__ __align__(16) char shb[33792];
  int b = blockIdx.x, tid = threadIdx.x;
  if (b < 512) {                      // Ksw: [pt][ks][lane][8]
    int pt = b;
    if (pt * 16 >= pbTot[0]) return;
    auto Tk = (__bf16(*)[1040])shb;
    int rr = tid >> 4, lt = tid & 15;
    int src = pridx[pt * 16 + rr];
    for (int cc = 0; cc < 16; ++cc) {
      int i4 = cc * 16 + lt;
      f4 v = {0.f, 0.f, 0.f, 0.f};
      if (src >= 0) v = ((const f4*)(wk + (size_t)src * Hh))[i4];
      bf4 o = {(__bf16)v[0], (__bf16)v[1], (__bf16)v[2], (__bf16)v[3]};
      *(bf4*)&Tk[rr][i4 * 4] = o;
    }
    __syncthreads();
#pragma unroll
    for (int i = 0; i < 8; ++i) {
      int f = tid + 256 * i;
      int ks = f >> 6, ln = f & 63;
      int c2 = ln & 15, rg2 = ln >> 4;
      bf8 o = *(const bf8*)&Tk[c2][ks * 32 + rg2 * 8];
      *(bf8*)&Ksw[(size_t)pt * 16384 + (size_t)f * 8] = o;
    }
  } else {                            // Vsw: [pblk][ff][lane][8]
    int pblk = b - 512;
    if (pblk * 32 >= pbTot[0]) return;
    auto Tv = (__bf16(*)[528])shb;
    int rr = tid >> 3, lt = tid & 7;
    int src = pridx[pblk * 32 + rr];
    for (int cc = 0; cc < 16; ++cc) {
      int i4 = cc * 8 + lt;
      f4 v = {0.f, 0.f, 0.f, 0.f};
      if (src >= 0) v = ((const f4*)(wv_ + (size_t)src * D_EMB))[i4];
      bf4 o = {(__bf16)v[0], (__bf16)v[1], (__bf16)v[2], (__bf16)v[3]};
      *(bf4*)&Tv[rr][i4 * 4] = o;
    }
    __syncthreads();
#pragma unroll
    for (int i = 0; i < 8; ++i) {
      int f = tid + 256 * i;
      int ff = f >> 6, ln = f & 63;
      int c2 = ln & 15, rg2 = ln >> 4;
      bf8 o;
#pragma unroll
      for (int j = 0; j < 8; ++j) o[j] = Tv[rg2 * 8 + j][ff * 16 + c2];
      *(bf8*)&Vsw[(size_t)pblk * 16384 + (size_t)f * 8] = o;
    }
  }
}

// ---------------- RMSNorm of input: inb[j] = bf16(input[j]); Qsw row gq[bw[j]] ----------------
__global__ __launch_bounds__(256) void rms_in_kernel(const float* __restrict__ input,
                                                     const int* __restrict__ bw,
                                                     const int* __restrict__ gq,
                                                     const float* __restrict__ wn,
                                                     __bf16* __restrict__ Qsw,
                                                     __bf16* __restrict__ inb) {
  __shared__ __align__(16) __bf16 rowbuf[4][1024];
  int wv = threadIdx.x >> 6, lane = threadIdx.x & 63;
  int j = blockIdx.x * 4 + wv;
  const f4* src = (const f4*)(input + (size_t)j * Hh);
  f4 v[4];
  float ss = 0.f;
#pragma unroll
  for (int c = 0; c < 4; ++c) {
    v[c] = src[c * 64 + lane];
    ss += v[c][0] * v[c][0] + v[c][1] * v[c][1] + v[c][2] * v[c][2] + v[c][3] * v[c][3];
  }
#pragma unroll
  for (int off = 32; off; off >>= 1) ss += __shfl_xor(ss, off);
  float sc = rsqrtf(ss * (1.f / Hh) + 1e-6f);
  bf4* dstI = (bf4*)(inb + (size_t)j * Hh);
#pragma unroll
  for (int c = 0; c < 4; ++c) {
    bf4 o = {(__bf16)v[c][0], (__bf16)v[c][1], (__bf16)v[c][2], (__bf16)v[c][3]};
    dstI[c * 64 + lane] = o;
  }
  const f4* w4 = (const f4*)wn;
#pragma unroll
  for (int c = 0; c < 4; ++c) {
    f4 w = w4[c * 64 + lane];
    bf4 o = {(__bf16)(v[c][0] * sc * w[0]), (__bf16)(v[c][1] * sc * w[1]),
             (__bf16)(v[c][2] * sc * w[2]), (__bf16)(v[c][3] * sc * w[3])};
    *(bf4*)&rowbuf[wv][(c * 64 + lane) * 4] = o;
  }
  int gpos = gq[bw[j]];
  int qt2 = gpos >> 4, cq = gpos & 15;
#pragma unroll
  for (int h = 0; h < 2; ++h) {
    int k_ = lane + h * 64;
    int ks = k_ >> 2, rg2 = k_ & 3;
    bf8 o = *(const bf8*)&rowbuf[wv][ks * 32 + rg2 * 8];
    *(bf8*)(Qsw + (size_t)qt2 * 16384 + ks * 512 + (cq + 16 * rg2) * 8) = o;
  }
}

// ---------------- cooperative 4-wave attention (proven round-8 structure) ----------------
__global__ __launch_bounds__(256, 3) void attn7_kernel(const __bf16* __restrict__ Qsw,
                                                       const __bf16* __restrict__ Ksw,
                                                       const __bf16* __restrict__ Vsw,
                                                       const int* __restrict__ qg2,
                                                       const int* __restrict__ qtot,
                                                       const int* __restrict__ ptq,
                                                       const int* __restrict__ taskS,
                                                       const int* __restrict__ taskT,
                                                       const int* __restrict__ nttA,
                                                       const int* __restrict__ pb,
                                                       const int* __restrict__ loP,
                                                       const int* __restrict__ hiP,
                                                       const int* __restrict__ fw,
                                                       __bf16* __restrict__ comb) {
  __shared__ float Sb[16][66];
  __shared__ __align__(16) __bf16 Plds[16][72];
  __shared__ float scl_s[16], lrec[16];
  __shared__ __align__(16) __bf16 owb[16][528];
  int t = blockIdx.x;
  if (t >= nttA[0]) return;
  int tid = threadIdx.x, wv = tid >> 6, lane = tid & 63;
  int c = lane & 15, rg = lane >> 4;
  int s = taskS[t], tl = taskT[t];
  int qtp = ptq[s] + tl;
  int qcnt = min(16, qtot[s] - tl * 16);
  bool qv = c < qcnt;
  int q_l = qg2[qtp * 16 + (qv ? c : 0)];
  int n_l = q_l >> 9;
  int lo_l = qv ? loP[n_l * KL + s] : 0x7fffffff;
  int hi_l = qv ? hiP[n_l * KL + s] : 0;
  int tlo = lo_l, thi = hi_l;
#pragma unroll
  for (int off = 1; off < 64; off <<= 1) {
    tlo = min(tlo, __shfl_xor(tlo, off));
    thi = max(thi, __shfl_xor(thi, off));
  }
  if (tlo >= thi) return;
  int pbs = pb[s];
  const __bf16* Qb = Qsw + (size_t)qtp * 16384 + lane * 8;

  float m[4] = {-1e30f, -1e30f, -1e30f, -1e30f};
  float l[4] = {0.f, 0.f, 0.f, 0.f};
  f32x4 acc[8];
  f32x4 zero = {0.f, 0.f, 0.f, 0.f};
#pragma unroll
  for (int tt = 0; tt < 8; ++tt) acc[tt] = zero;

  int p0beg = pbs + ((tlo - pbs) & ~63);
  for (int p0 = p0beg; p0 < thi; p0 += 64) {
    const __bf16* Kb = Ksw + (size_t)((p0 >> 4) + wv) * 16384 + lane * 8;
    f32x4 sacc = zero;
#pragma unroll
    for (int ks = 0; ks < 32; ++ks) {
      bf8 qf = *(const bf8*)(Qb + ks * 512);
      bf8 kf = *(const bf8*)(Kb + ks * 512);
      sacc = __builtin_amdgcn_mfma_f32_16x16x32_bf16(kf, qf, sacc, 0, 0, 0);
    }
#pragma unroll
    for (int r = 0; r < 4; ++r) {
      int kv = p0 + wv * 16 + rg * 4 + r;
      Sb[c][wv * 16 + rg * 4 + r] = (kv >= lo_l && kv < hi_l) ? sacc[r] : -1e30f;
    }
    __syncthreads();

#pragma unroll
    for (int r = 0; r < 4; ++r) {
      int q = wv * 4 + r;
      float sv = Sb[q][lane];
      float cm = sv;
#pragma unroll
      for (int off = 32; off; off >>= 1) cm = fmaxf(cm, __shfl_xor(cm, off));
      float mn = fmaxf(m[r], cm);
      float sc2 = __expf(m[r] - mn);
      float pv = __expf(sv - mn);
      float ssum = pv;
#pragma unroll
      for (int off = 32; off; off >>= 1) ssum += __shfl_xor(ssum, off);
      l[r] = l[r] * sc2 + ssum;
      m[r] = mn;
      Plds[q][lane] = (__bf16)pv;
      if (lane == 0) scl_s[q] = sc2;
    }
    __syncthreads();

    float sf = scl_s[c];
#pragma unroll
    for (int tt = 0; tt < 8; ++tt) acc[tt] = acc[tt] * sf;
    bf8 pa0 = *(const bf8*)&Plds[c][rg * 8];
    bf8 pa1 = *(const bf8*)&Plds[c][32 + rg * 8];
    const __bf16* Vb = Vsw + (size_t)(p0 >> 5) * 16384 + lane * 8;
#pragma unroll
    for (int tt = 0; tt < 8; ++tt) {
      int ff = wv * 8 + tt;
      bf8 v0 = *(const bf8*)(Vb + ff * 512);
      bf8 v1 = *(const bf8*)(Vb + 16384 + ff * 512);
      acc[tt] = __builtin_amdgcn_mfma_f32_16x16x32_bf16(v0, pa0, acc[tt], 0, 0, 0);
      acc[tt] = __builtin_amdgcn_mfma_f32_16x16x32_bf16(v1, pa1, acc[tt], 0, 0, 0);
    }
    __syncthreads();
  }

  if (lane == 0) {
#pragma unroll
    for (int r = 0; r < 4; ++r) lrec[wv * 4 + r] = l[r];
  }
  __syncthreads();
  float inv = 1.f / lrec[c];
#pragma unroll
  for (int tt = 0; tt < 8; ++tt) {
    bf4 o;
#pragma unroll
    for (int r = 0; r < 4; ++r) o[r] = (__bf16)(acc[tt][r] * inv);
    *(bf4*)&owb[c][(wv * 8 + tt) * 16 + rg * 4] = o;
  }
  __syncthreads();
#pragma unroll
  for (int r4 = 0; r4 < 4; ++r4) {
    int q2 = wv * 4 + r4;
    if (q2 < qcnt) {
      size_t ob = (size_t)fw[qg2[qtp * 16 + q2]] * D_EMB;
      *(bf8*)(comb + ob + lane * 8) = *(const bf8*)&owb[q2][lane * 8];
    }
  }
}

// ---------------- 256x256 ring GEMM + fused ssq-accumulate / rs-apply ----------------
// SSQ: epilogue accumulates per-row sum of squares (up GEMM).
// RS:  after tile rsTile, scale acc rows by rsqrt(ssq/2048+eps) (mix GEMM).
template <bool OUT_BF16, bool SSQ, bool RS>
__global__ __launch_bounds__(512, 2) void gemm10(const __bf16* __restrict__ x0, int k0,
                                                 const __bf16* __restrict__ x1, int k1,
                                                 const __bf16* __restrict__ w,
                                                 void* __restrict__ outp, int Mt, int Nt,
                                                 float* __restrict__ rowssq, int rsTile) {
  __shared__ __align__(16) __bf16 lds[4][2][256 * 32];
  const int nwg = Mt * Nt;
  const int bid = blockIdx.x;
  const int swz = (bid % NXCD) * (nwg / NXCD) + bid / NXCD;
  const int m0 = (swz / Nt) * 256, n0 = (swz % Nt) * 256;
  const int K = k0 + k1;
  const int NT = K >> 5;
  const int N = Nt * 256;
  const int tid = threadIdx.x, lane = tid & 63, wvi = tid >> 6;
  const int wr = wvi >> 2, wc = wvi & 3;
  const int srow = tid >> 2;
  const int spb = (tid & 3) * 16;
  const int c = lane & 15, rg = lane >> 4;
  const int fa_off = c * 64 + ((rg ^ ((c >> 1) & 3)) << 4);
  const int r0 = (lane >> 4) * 4;

  auto stage = [&](int t) {
    int kg = t * 32;
    const __bf16* xs;
    int ld, kk;
    if (kg < k0) { xs = x0; ld = k0; kk = kg; }
    else         { xs = x1; ld = k1; kk = kg - k0; }
    int b = t & 3;
#pragma unroll
    for (int j = 0; j < 2; ++j) {
      int r = j * 128 + srow;
      int lcol = (spb ^ (((r >> 1) & 3) << 4)) >> 1;
      gl_lds16(xs + (size_t)(m0 + r) * ld + kk + lcol,
               (void*)((char*)&lds[b][0][0] + r * 64 + spb));
      gl_lds16(w + (size_t)(n0 + r) * K + kg + lcol,
               (void*)((char*)&lds[b][1][0] + r * 64 + spb));
    }
  };

  f32x4 acc[8][4];
  f32x4 zero = {0.f, 0.f, 0.f, 0.f};
#pragma unroll
  for (int a = 0; a < 8; ++a)
#pragma unroll
    for (int bnx = 0; bnx < 4; ++bnx) acc[a][bnx] = zero;

  auto compute = [&](int t) {
    const char* Ab = (const char*)&lds[t & 3][0][0];
    const char* Bb = (const char*)&lds[t & 3][1][0];
    bf8 afr[8], bfr[4];
#pragma unroll
    for (int fi = 0; fi < 8; ++fi)
      afr[fi] = *(const bf8*)(Ab + (wr * 128 + fi * 16) * 64 + fa_off);
#pragma unroll
    for (int ni = 0; ni < 4; ++ni)
      bfr[ni] = *(const bf8*)(Bb + (wc * 64 + ni * 16) * 64 + fa_off);
    __builtin_amdgcn_s_setprio(1);
#pragma unroll
    for (int fi = 0; fi < 8; ++fi)
#pragma unroll
      for (int ni = 0; ni < 4; ++ni)
        acc[fi][ni] = __builtin_amdgcn_mfma_f32_16x16x32_bf16(afr[fi], bfr[ni], acc[fi][ni], 0, 0, 0);
    __builtin_amdgcn_s_setprio(0);
  };

  auto apply_rs = [&]() {
#pragma unroll
    for (int mi = 0; mi < 8; ++mi) {
      int base = m0 + wr * 128 + mi * 16 + r0;
#pragma unroll
      for (int r = 0; r < 4; ++r) {
        float rsv = rsqrtf(rowssq[base + r] * (1.f / 2048.f) + 1e-6f);
#pragma unroll
        for (int ni = 0; ni < 4; ++ni) acc[mi][ni][r] *= rsv;
      }
    }
  };

  stage(0); stage(1); stage(2);
  asm volatile("s_waitcnt vmcnt(8)" ::: "memory");
  __builtin_amdgcn_s_barrier();

  for (int t = 0; t < NT - 3; ++t) {
    stage(t + 3);
    compute(t);
    if (RS) { if (t == rsTile) apply_rs(); }
    asm volatile("s_waitcnt vmcnt(8)" ::: "memory");
    __builtin_amdgcn_s_barrier();
  }
  compute(NT - 3);
  if (RS) { if (NT - 3 == rsTile) apply_rs(); }
  asm volatile("s_waitcnt vmcnt(4)" ::: "memory");
  __builtin_amdgcn_s_barrier();
  compute(NT - 2);
  if (RS) { if (NT - 2 == rsTile) apply_rs(); }
  asm volatile("s_waitcnt vmcnt(0)" ::: "memory");
  __builtin_amdgcn_s_barrier();
  compute(NT - 1);

  if (SSQ) {
#pragma unroll
    for (int mi = 0; mi < 8; ++mi) {
      float p[4];
#pragma unroll
      for (int r = 0; r < 4; ++r) {
        float a = 0.f;
#pragma unroll
        for (int ni = 0; ni < 4; ++ni) a += acc[mi][ni][r] * acc[mi][ni][r];
        p[r] = a;
      }
#pragma unroll
      for (int off = 1; off < 16; off <<= 1)
#pragma unroll
        for (int r = 0; r < 4; ++r) p[r] += __shfl_xor(p[r], off);
      if ((lane & 15) == 0) {
        int base = m0 + wr * 128 + mi * 16 + r0;
#pragma unroll
        for (int r = 0; r < 4; ++r) atomicAdd(&rowssq[base + r], p[r]);
      }
    }
  }

  const int cc = lane & 15;
#pragma unroll
  for (int mi = 0; mi < 8; ++mi) {
    int rowb = m0 + wr * 128 + mi * 16 + r0;
#pragma unroll
    for (int ni = 0; ni < 4; ++ni) {
      int col = n0 + wc * 64 + ni * 16 + cc;
#pragma unroll
      for (int r = 0; r < 4; ++r) {
        float v = acc[mi][ni][r];
        if (OUT_BF16)
          ((__bf16*)outp)[(size_t)(rowb + r) * N + col] = (__bf16)v;
        else
          ((float*)outp)[(size_t)(rowb + r) * N + col] = v;
      }
    }
  }
}

// ---------------- launch ----------------
extern "C" void kernel_launch(void* const* d_in, const int* in_sizes, int n_in, void* d_out,
                              int out_size, void* d_ws, size_t ws_size, hipStream_t stream) {
  const float* input = (const float*)d_in[0];
  const int* fw = (const int*)d_in[1];
  const int* bw = (const int*)d_in[2];
  const int* seq_sort = (const int*)d_in[3];
  const int* keep_cols = (const int*)d_in[4];
  const int* emb_alloc = (const int*)d_in[5];
  const int* starts = (const int*)d_in[6];
  const int* ends = (const int*)d_in[7];
  const float* w_k = (const float*)d_in[9];
  const float* w_v = (const float*)d_in[10];
  const float* w_up = (const float*)d_in[11];
  const float* w_mix = (const float*)d_in[12];
  const float* w_nin = (const float*)d_in[13];
  const float* w_nout = (const float*)d_in[14];

  char* p = (char*)d_ws;
  auto take = [&](size_t b) {
    void* r = (void*)p;
    p += (b + 255) & ~(size_t)255;
    return r;
  };
  // region A: persistent through the whole pipeline
  __bf16* inb = (__bf16*)take((size_t)BT * Hh * 2);
  __bf16* comb = (__bf16*)take((size_t)BT * D_EMB * 2);
  __bf16* wupB = (__bf16*)take((size_t)D_UP * D_EMB * 2);
  __bf16* wmixB = (__bf16*)take((size_t)Hh * (D_UP + Hh) * 2);
  float* rowssq = (float*)take((size_t)BT * 4);
  // region B: attention-phase only; `up` aliases it afterwards
  char* pB = p;
  __bf16* Ksw = (__bf16*)take((size_t)PMMAX * 1024 * 2);
  __bf16* Vsw = (__bf16*)take((size_t)PMMAX * 512 * 2);
  __bf16* Qsw = (__bf16*)take((size_t)QROWMAX * 1024 * 2);
  int* la = (int*)take(Mm * 4);
  int* stA = (int*)take(NB * 4);
  int* enA = (int*)take(NB * 4);
  int* goff = (int*)take((KL + 1) * 4);
  int* gk = (int*)take(Mm * 4);
  int* ridx = (int*)take(Mm * 4);
  int* pridx = (int*)take(PMMAX * 4);
  int* loA = (int*)take(NB * KL * 4);
  int* hiA = (int*)take(NB * KL * 4);
  int* qidx = (int*)take(BT * 4);
  int* qoffA = (int*)take(NB * KL * 4);
  int* qcntA = (int*)take(NB * KL * 4);
  int* boff = (int*)take(NB * KL * 4);
  int* qtot = (int*)take(KL * 4);
  int* ptq = (int*)take((KL + 1) * 4);
  int* pb = (int*)take(KL * 4);
  int* taskS = (int*)take(MAXT * 4);
  int* taskT = (int*)take(MAXT * 4);
  int* ntt = (int*)take(4);
  int* pbTot = (int*)take(4);
  int* qg2 = (int*)take(QROWMAX * 4);
  int* gq = (int*)take(BT * 4);
  __bf16* up = (__bf16*)pB;  // aliases region B (dead after attn7)

  k1_misc<<<4192, 256, 0, stream>>>(w_up, w_mix, w_nout, keep_cols, emb_alloc, starts, ends,
                                    seq_sort, wupB, wmixB, la, stA, enA, qidx, qoffA, qcntA,
                                    rowssq);
  k2_meta<<<1, 256, 0, stream>>>(la, qcntA, goff, boff, qtot, ptq, pb, taskS, taskT, ntt, pbTot);
  place_kernel<<<KL, 256, 0, stream>>>(la, keep_cols, goff, gk, ridx);
  k4_idx<<<200, 256, 0, stream>>>(goff, pb, ridx, pridx, gk, stA, enA, loA, hiA, qidx, qoffA,
                                  seq_sort, boff, ptq, qg2, gq, qtot, Qsw);
  k5_build<<<768, 256, 0, stream>>>(w_k, w_v, pridx, pbTot, Ksw, Vsw);
  rms_in_kernel<<<BT / 4, 256, 0, stream>>>(input, bw, gq, w_nin, Qsw, inb);
  attn7_kernel<<<MAXT, 256, 0, stream>>>(Qsw, Ksw, Vsw, qg2, qtot, ptq, taskS, taskT, ntt, pb,
                                         loA, hiA, fw, comb);
  gemm10<true, true, false><<<BT / 256 * (D_UP / 256), 512, 0, stream>>>(
      comb, D_EMB, (const __bf16*)nullptr, 0, wupB, (void*)up, BT / 256, D_UP / 256, rowssq, -1);
  gemm10<false, false, true><<<BT / 256 * (Hh / 256), 512, 0, stream>>>(
      up, D_UP, inb, Hh, wmixB, d_out, BT / 256, Hh / 256, rowssq, 63);
}